// Round 1
// baseline (433.430 us; speedup 1.0000x reference)
//
#include <hip/hip_runtime.h>
#include <cstdint>

typedef unsigned short ushort_t;
typedef unsigned int uint_t;
typedef _Float16 f16x8 __attribute__((ext_vector_type(8)));
typedef float f32x4 __attribute__((ext_vector_type(4)));

#define N_ROWS 32768
#define DK 512
#define NC_MAIN 1024
#define NCB 1792  // 1024 + 512 + 256
#define NTILE 14  // 1792 / 128 (candidate tile granularity, unchanged)
#define NBLK_RG 8192  // rescue_gather blocks (4 rows each)

// d_out layout (floats, concatenated reference outputs)
#define MAIN_OFF 0
#define SUB_OFF  16777216
#define LOSS_OFF 33554432
#define MSK_OFF  33554433
#define UNIQ_OFF 33562625

__device__ __forceinline__ uint_t umin_(uint_t a, uint_t b) { return a < b ? a : b; }
__device__ __forceinline__ uint_t umax_(uint_t a, uint_t b) { return a > b ? a : b; }

// ---------------------------------------------------------------------------
// Build combined codebook CB[1792][512] (fp32) AND its f16 copy cbh.
// rows 0..1023 copy of c; 1024..1535 = W1@c+b1; 1536..1791 = W2@c+b2.
__global__ __launch_bounds__(256) void build_subcb(
    const float* __restrict__ c, const float* __restrict__ W1,
    const float* __restrict__ b1, const float* __restrict__ W2,
    const float* __restrict__ b2, float* __restrict__ CB,
    _Float16* __restrict__ cbh)
{
    int tid = threadIdx.x;
    int tx = tid & 63, ty = tid >> 6;
    int col = blockIdx.x * 64 + tx;
    int row0 = blockIdx.y * 16 + ty * 4;
    if (row0 < 1024) {
#pragma unroll
        for (int r = 0; r < 4; ++r) {
            float v = c[(row0 + r) * DK + col];
            CB[(row0 + r) * DK + col] = v;
            cbh[(row0 + r) * DK + col] = (_Float16)v;
        }
    } else {
        int i0 = row0 - 1024;
        const float* W;
        const float* b;
        if (i0 < 512) { W = W1; b = b1; }
        else          { W = W2; b = b2; i0 -= 512; }
        float acc[4] = {0.f, 0.f, 0.f, 0.f};
#pragma unroll 8
        for (int j = 0; j < 1024; ++j) {
            float cv = c[j * DK + col];
#pragma unroll
            for (int r = 0; r < 4; ++r)
                acc[r] += W[(i0 + r) * 1024 + j] * cv;
        }
#pragma unroll
        for (int r = 0; r < 4; ++r) {
            float v = acc[r] + b[i0 + r];
            CB[(row0 + r) * DK + col] = v;
            cbh[(row0 + r) * DK + col] = (_Float16)v;
        }
    }
}

// ---------------------------------------------------------------------------
__global__ __launch_bounds__(64) void row_norms(const float* __restrict__ CB,
                                                float* __restrict__ norms) {
    int row = blockIdx.x;
    int lane = threadIdx.x;
    const float4* p = (const float4*)(CB + (size_t)row * DK);
    float s = 0.f;
#pragma unroll
    for (int i = lane; i < 128; i += 64) {
        float4 v = p[i];
        s += v.x * v.x + v.y * v.y + v.z * v.z + v.w * v.w;
    }
#pragma unroll
    for (int off = 32; off; off >>= 1) s += __shfl_down(s, off, 64);
    if (lane == 0) norms[row] = s;
}

// ---------------------------------------------------------------------------
// fp32 -> f16 (RN) for x, 8 elems/thread; also zeroes `used` (init fused).
__global__ __launch_bounds__(256) void cvt_x(const float* __restrict__ in,
                                             _Float16* __restrict__ out,
                                             int* __restrict__ used) {
    int i = blockIdx.x * 256 + threadIdx.x;
    if (i < 1024) used[i] = 0;
    const float4* p = (const float4*)in + (size_t)i * 2;
    float4 a = p[0], b = p[1];
    f16x8 o;
    o[0] = (_Float16)a.x; o[1] = (_Float16)a.y; o[2] = (_Float16)a.z; o[3] = (_Float16)a.w;
    o[4] = (_Float16)b.x; o[5] = (_Float16)b.y; o[6] = (_Float16)b.z; o[7] = (_Float16)b.w;
    *((f16x8*)out + i) = o;
}

// ---------------------------------------------------------------------------
__device__ __forceinline__ void async16(void* lds, const void* g) {
    __builtin_amdgcn_global_load_lds(
        (const __attribute__((address_space(1))) unsigned int*)(uintptr_t)g,
        (__attribute__((address_space(3))) unsigned int*)(uintptr_t)lds,
        16, 0, 0);
}

// ---------------------------------------------------------------------------
// MFMA f16 GEMM S = xh . cbh^T, 8-phase 256x256 schedule (HK/m201 template)
// with per-(row, 128-col-tile) top-2 epilogue feeding candbuf (layout
// unchanged: NTILE=14 tiles of 128 cols, top-2 keys each).
//
// Geometry: BM=BN=256, BK=64, 512 thr = 8 waves (2M x 4N), per-wave 128x64.
// LDS 128 KiB: As/Bs[2 dbuf][2 ksub][256*32] f16 (each half-tile = 16 KiB
// contiguous so global_load_lds dest stays lane-linear).
// T2 swizzle (involution; mask uses only row bits it doesn't modify):
//   byte' = byte ^ (((row>>1)&3)<<4) ^ (((row>>3)&1)<<6)
// applied to the pre-swizzled GLOBAL source on stage and to ds_read addrs.
// Gives exact 2-way (free) bank access for all b128 fragment reads.
// T3/T4: 4 phases/K-tile {ds_read; stage 1 half-tile; bar; lgkm0; 16 MFMA;
// bar}; each phase stages the half-tile slot freed in the previous phase
// (7-phase issue-to-need distance); vmcnt(6) once per K-tile boundary;
// prologue: stage 4 halves, vmcnt(4), stage 3, vmcnt(6); drain vmcnt(0)
// entering the last K-tile. T5: setprio(1) around MFMA clusters.
__global__ __launch_bounds__(512, 2) void gemm_topk(
    const _Float16* __restrict__ xh, const _Float16* __restrict__ cbh,
    const float* __restrict__ norms, uint2* __restrict__ candbuf)
{
    __shared__ __align__(16) ushort_t As[2][2][256 * 32];  // 64 KiB
    __shared__ __align__(16) ushort_t Bs[2][2][256 * 32];  // 64 KiB

    const int tid = threadIdx.x;
    const int lane = tid & 63;
    const int wid = tid >> 6;
    const int wy = wid >> 2, wx = wid & 3;
    const int lane15 = lane & 15, q = lane >> 4;

    // XCD-aware remap: 896 blocks = 8 xcd * 112 slots; same-xcd consecutive
    // slots share an A row-strip (7 tileP each) -> strip stays in that XCD L2.
    const int bid = blockIdx.x;
    const int xcd = bid & 7;
    const int slot = bid >> 3;            // 0..111
    const int tileP = slot % 7;           // 256-col pair-tile 0..6
    const int rowG = slot / 7;            // 0..15
    const int rowBase = (rowG * 8 + xcd) * 256;
    const int c0 = tileP * 256;

    // staging: linear LDS dest, inverse-swizzled global source.
    size_t aoff[2], boff[2];
    int ldsd[2];
#pragma unroll
    for (int i = 0; i < 2; ++i) {
        int d16 = i * 512 + tid;          // 16B granule index in 16KiB region
        int row = d16 >> 2, g = d16 & 3;
        int srow = row ^ ((row >> 3) & 1);
        int sg = g ^ ((row >> 1) & 3);
        aoff[i] = (size_t)(rowBase + srow) * DK + (size_t)(sg * 8);
        boff[i] = (size_t)(c0 + srow) * DK + (size_t)(sg * 8);
        ldsd[i] = d16 * 8;                // f16 elements
    }

#define STG_A(BUF, KS, KT) do { \
        async16(&As[(BUF)][(KS)][ldsd[0]], xh + aoff[0] + (KT) * 64 + (KS) * 32); \
        async16(&As[(BUF)][(KS)][ldsd[1]], xh + aoff[1] + (KT) * 64 + (KS) * 32); \
    } while (0)
#define STG_B(BUF, KS, KT) do { \
        async16(&Bs[(BUF)][(KS)][ldsd[0]], cbh + boff[0] + (KT) * 64 + (KS) * 32); \
        async16(&Bs[(BUF)][(KS)][ldsd[1]], cbh + boff[1] + (KT) * 64 + (KS) * 32); \
    } while (0)

    // swizzled fragment read offsets (f16 units within one [256][32] region)
    int rdA[8], rdB[4];
#pragma unroll
    for (int mr = 0; mr < 8; ++mr) {
        int rl = wy * 128 + mr * 16 + lane15;
        rdA[mr] = (rl ^ ((rl >> 3) & 1)) * 32 + (q ^ ((rl >> 1) & 3)) * 8;
    }
#pragma unroll
    for (int nc = 0; nc < 4; ++nc) {
        int cl = wx * 64 + nc * 16 + lane15;
        rdB[nc] = (cl ^ ((cl >> 3) & 1)) * 32 + (q ^ ((cl >> 1) & 3)) * 8;
    }

    f32x4 acc[8][4];
#pragma unroll
    for (int mr = 0; mr < 8; ++mr)
#pragma unroll
        for (int nc = 0; nc < 4; ++nc) acc[mr][nc] = (f32x4)0.f;

    // ---- prologue: tile0 fully + first 3 halves of tile1 ----
    STG_B(0, 0, 0); STG_A(0, 0, 0); STG_B(0, 1, 0); STG_A(0, 1, 0);
    asm volatile("s_waitcnt vmcnt(4)" ::: "memory");   // B00,A00 landed
    STG_B(1, 0, 1); STG_A(1, 0, 1); STG_B(1, 1, 1);
    asm volatile("s_waitcnt vmcnt(6)" ::: "memory");   // tile0 fully landed
    __builtin_amdgcn_s_barrier();

    f16x8 av[4], bv[4];
#pragma unroll
    for (int t = 0; t < 8; ++t) {
        const int b = t & 1;
        // -------- phase 1: ks0, mr 0..3 (+ all B ks0); stage A-ks1(t+1) ----
#pragma unroll
        for (int nc = 0; nc < 4; ++nc) bv[nc] = *(const f16x8*)&Bs[b][0][rdB[nc]];
#pragma unroll
        for (int mr = 0; mr < 4; ++mr) av[mr] = *(const f16x8*)&As[b][0][rdA[mr]];
        if (t + 1 < 8) STG_A(b ^ 1, 1, t + 1);
        __builtin_amdgcn_sched_barrier(0);
        __builtin_amdgcn_s_barrier();
        asm volatile("s_waitcnt lgkmcnt(0)" ::: "memory");
        __builtin_amdgcn_sched_barrier(0);
        __builtin_amdgcn_s_setprio(1);
#pragma unroll
        for (int mr = 0; mr < 4; ++mr)
#pragma unroll
            for (int nc = 0; nc < 4; ++nc)
                acc[mr][nc] = __builtin_amdgcn_mfma_f32_16x16x32_f16(
                    av[mr], bv[nc], acc[mr][nc], 0, 0, 0);
        __builtin_amdgcn_s_setprio(0);
        __builtin_amdgcn_sched_barrier(0);
        __builtin_amdgcn_s_barrier();
        // -------- phase 2: ks0, mr 4..7; stage B-ks0(t+2) ------------------
#pragma unroll
        for (int mr = 0; mr < 4; ++mr) av[mr] = *(const f16x8*)&As[b][0][rdA[4 + mr]];
        if (t + 2 < 8) STG_B(b, 0, t + 2);
        __builtin_amdgcn_sched_barrier(0);
        __builtin_amdgcn_s_barrier();
        asm volatile("s_waitcnt lgkmcnt(0)" ::: "memory");
        __builtin_amdgcn_sched_barrier(0);
        __builtin_amdgcn_s_setprio(1);
#pragma unroll
        for (int mr = 0; mr < 4; ++mr)
#pragma unroll
            for (int nc = 0; nc < 4; ++nc)
                acc[4 + mr][nc] = __builtin_amdgcn_mfma_f32_16x16x32_f16(
                    av[mr], bv[nc], acc[4 + mr][nc], 0, 0, 0);
        __builtin_amdgcn_s_setprio(0);
        __builtin_amdgcn_sched_barrier(0);
        __builtin_amdgcn_s_barrier();
        // -------- phase 3: ks1, mr 0..3 (+ all B ks1); stage A-ks0(t+2) ----
#pragma unroll
        for (int nc = 0; nc < 4; ++nc) bv[nc] = *(const f16x8*)&Bs[b][1][rdB[nc]];
#pragma unroll
        for (int mr = 0; mr < 4; ++mr) av[mr] = *(const f16x8*)&As[b][1][rdA[mr]];
        if (t + 2 < 8) STG_A(b, 0, t + 2);
        __builtin_amdgcn_sched_barrier(0);
        __builtin_amdgcn_s_barrier();
        asm volatile("s_waitcnt lgkmcnt(0)" ::: "memory");
        __builtin_amdgcn_sched_barrier(0);
        __builtin_amdgcn_s_setprio(1);
#pragma unroll
        for (int mr = 0; mr < 4; ++mr)
#pragma unroll
            for (int nc = 0; nc < 4; ++nc)
                acc[mr][nc] = __builtin_amdgcn_mfma_f32_16x16x32_f16(
                    av[mr], bv[nc], acc[mr][nc], 0, 0, 0);
        __builtin_amdgcn_s_setprio(0);
        __builtin_amdgcn_sched_barrier(0);
        __builtin_amdgcn_s_barrier();
        // -------- phase 4: ks1, mr 4..7; stage B-ks1(t+2); tile gate -------
#pragma unroll
        for (int mr = 0; mr < 4; ++mr) av[mr] = *(const f16x8*)&As[b][1][rdA[4 + mr]];
        if (t + 2 < 8) STG_B(b, 1, t + 2);
        __builtin_amdgcn_sched_barrier(0);
        __builtin_amdgcn_s_barrier();
        asm volatile("s_waitcnt lgkmcnt(0)" ::: "memory");
        __builtin_amdgcn_sched_barrier(0);
        __builtin_amdgcn_s_setprio(1);
#pragma unroll
        for (int mr = 0; mr < 4; ++mr)
#pragma unroll
            for (int nc = 0; nc < 4; ++nc)
                acc[4 + mr][nc] = __builtin_amdgcn_mfma_f32_16x16x32_f16(
                    av[mr], bv[nc], acc[4 + mr][nc], 0, 0, 0);
        __builtin_amdgcn_s_setprio(0);
        // tile-boundary vmcnt gate: next tile's 4 halves must be landed in
        // every wave before the barrier releases anyone into phase 1.
        if (t < 7) {
            if (t + 2 < 8) asm volatile("s_waitcnt vmcnt(6)" ::: "memory");
            else           asm volatile("s_waitcnt vmcnt(0)" ::: "memory");
        }
        __builtin_amdgcn_sched_barrier(0);
        __builtin_amdgcn_s_barrier();
    }
#undef STG_A
#undef STG_B

    // ---------------- epilogue: per-row top-2 per 128-col tile -------------
    // cand overlays As (all LDS reads drained before the final barrier).
    uint2 (*cand)[4] = (uint2(*)[4])(void*)&As[0][0][0];  // [256 rows][4 wx]

    float nrm[4];
    uint_t colGlob[4];
#pragma unroll
    for (int nc = 0; nc < 4; ++nc) {
        colGlob[nc] = (uint_t)(c0 + wx * 64 + nc * 16 + lane15);
        nrm[nc] = norms[colGlob[nc]];
    }

#pragma unroll
    for (int mr = 0; mr < 8; ++mr) {
#pragma unroll
        for (int r = 0; r < 4; ++r) {
            uint_t k[4];
#pragma unroll
            for (int nc = 0; nc < 4; ++nc) {
                float s = fmaf(-2.f, acc[mr][nc][r], nrm[nc]);
                uint_t bb = __float_as_uint(s);
                uint_t u = bb ^ ((uint_t)((int)bb >> 31) | 0x80000000u);
                k[nc] = (u & 0xFFFFF800u) | colGlob[nc];
            }
            uint_t lo01 = umin_(k[0], k[1]), hi01 = umax_(k[0], k[1]);
            uint_t lo23 = umin_(k[2], k[3]), hi23 = umax_(k[2], k[3]);
            uint_t k1 = umin_(lo01, lo23);
            uint_t k2 = umin_(umin_(hi01, hi23), umax_(lo01, lo23));
#pragma unroll
            for (int m = 1; m <= 8; m <<= 1) {
                uint_t o1 = __shfl_xor(k1, m, 64);
                uint_t o2 = __shfl_xor(k2, m, 64);
                uint_t n1 = umin_(k1, o1);
                uint_t n2 = umin_(umax_(k1, o1), umin_(k2, o2));
                k1 = n1; k2 = n2;
            }
            if (lane15 == 0) {
                int rloc = wy * 128 + mr * 16 + q * 4 + r;
                cand[rloc][wx] = make_uint2(k1, k2);
            }
        }
    }
    __syncthreads();
    {
        int half = tid >> 8;        // 0..1 -> which 128-col tile of the pair
        int row = tid & 255;
        uint2 a = cand[row][half * 2], b2 = cand[row][half * 2 + 1];
        uint_t k1 = umin_(a.x, b2.x);
        uint_t k2 = umin_(umax_(a.x, b2.x), umin_(a.y, b2.y));
        candbuf[(size_t)(rowBase + row) * NTILE + (tileP * 2 + half)] =
            make_uint2(k1, k2);
    }
}

// ---------------------------------------------------------------------------
// Per x-row: merge tile candidate keys per segment (top-4, pure u32 min/max on
// wave-uniform values), rescore exactly in fp32, pick argmin (tie -> lowest
// idx; idx lives in key low bits so key order matches), gather rows, write
// outputs, per-block loss partials, mark used. One wave per row.
__device__ __forceinline__ void push4u(uint_t v, uint_t* bs) {
#pragma unroll
    for (int j = 0; j < 4; ++j) {
        uint_t lo = umin_(v, bs[j]);
        uint_t hi = umax_(v, bs[j]);
        bs[j] = lo; v = hi;
    }
}

__global__ __launch_bounds__(256) void rescue_gather(
    const float* __restrict__ x, const float* __restrict__ CB,
    const float* __restrict__ norms, const uint2* __restrict__ candbuf,
    float* __restrict__ main_out, float* __restrict__ sub_out,
    float2* __restrict__ lossPart, int* __restrict__ used)
{
    const int lane = threadIdx.x & 63;
    const int wv = threadIdx.x >> 6;
    const int r = blockIdx.x * 4 + wv;

    const float4* xp = (const float4*)(x + (size_t)r * DK) + lane * 2;
    float4 xa = xp[0], xb = xp[1];

    const uint2* cbp = candbuf + (size_t)r * NTILE;

    int si[12];
    {
        uint_t bs[4];
        // main: tiles 0..7
#pragma unroll
        for (int j = 0; j < 4; ++j) bs[j] = 0xFFFFFFFFu;
#pragma unroll
        for (int t = 0; t < 8; ++t) {
            uint2 e = cbp[t];
            push4u(__builtin_amdgcn_readfirstlane(e.x), bs);
            push4u(__builtin_amdgcn_readfirstlane(e.y), bs);
        }
#pragma unroll
        for (int j = 0; j < 4; ++j) si[j] = (int)(bs[j] & 2047u);
        // s1: tiles 8..11
#pragma unroll
        for (int j = 0; j < 4; ++j) bs[j] = 0xFFFFFFFFu;
#pragma unroll
        for (int t = 8; t < 12; ++t) {
            uint2 e = cbp[t];
            push4u(__builtin_amdgcn_readfirstlane(e.x), bs);
            push4u(__builtin_amdgcn_readfirstlane(e.y), bs);
        }
#pragma unroll
        for (int j = 0; j < 4; ++j) si[4 + j] = (int)(bs[j] & 2047u);
        // s2: tiles 12..13 (exactly 4 candidates)
#pragma unroll
        for (int j = 0; j < 4; ++j) bs[j] = 0xFFFFFFFFu;
#pragma unroll
        for (int t = 12; t < 14; ++t) {
            uint2 e = cbp[t];
            push4u(__builtin_amdgcn_readfirstlane(e.x), bs);
            push4u(__builtin_amdgcn_readfirstlane(e.y), bs);
        }
#pragma unroll
        for (int j = 0; j < 4; ++j) si[8 + j] = (int)(bs[j] & 2047u);
    }

    // exact fp32 dots for all 12 candidates
    float d[12];
#pragma unroll
    for (int k = 0; k < 12; ++k) {
        const float4* cp = (const float4*)(CB + (size_t)si[k] * DK) + lane * 2;
        float4 a = cp[0], b = cp[1];
        d[k] = xa.x * a.x + xa.y * a.y + xa.z * a.z + xa.w * a.w
             + xb.x * b.x + xb.y * b.y + xb.z * b.z + xb.w * b.w;
    }
#pragma unroll
    for (int off = 32; off; off >>= 1)
#pragma unroll
        for (int k = 0; k < 12; ++k) d[k] += __shfl_xor(d[k], off, 64);

    float sc[12];
#pragma unroll
    for (int k = 0; k < 12; ++k) sc[k] = norms[si[k]] - 2.f * d[k];

    int pick[3];
#pragma unroll
    for (int g = 0; g < 3; ++g) {
        float bv = sc[g * 4]; int bidx = si[g * 4];
#pragma unroll
        for (int k = 1; k < 4; ++k) {
            float v = sc[g * 4 + k]; int idx = si[g * 4 + k];
            if (v < bv || (v == bv && idx < bidx)) { bv = v; bidx = idx; }
        }
        pick[g] = bidx;
    }
    const int A = pick[0], B = pick[1], C = pick[2];

    // gather + write + loss
    const float4* pa = (const float4*)(CB + (size_t)A * DK) + lane * 2;
    const float4* pb = (const float4*)(CB + (size_t)B * DK) + lane * 2;
    const float4* pc = (const float4*)(CB + (size_t)C * DK) + lane * 2;
    float4* mo = (float4*)(main_out + (size_t)r * DK) + lane * 2;
    float4* so = (float4*)(sub_out + (size_t)r * DK) + lane * 2;
    float em = 0.f, es = 0.f;
#pragma unroll
    for (int i = 0; i < 2; ++i) {
        float4 xq = (i == 0) ? xa : xb;
        float4 cm = pa[i];
        float4 q1 = pb[i];
        float4 q2 = pc[i];
        float4 cs;
        cs.x = 0.5f * (q1.x + q2.x);
        cs.y = 0.5f * (q1.y + q2.y);
        cs.z = 0.5f * (q1.z + q2.z);
        cs.w = 0.5f * (q1.w + q2.w);
        mo[i] = cm;
        so[i] = cs;
        float t;
        t = cm.x - xq.x; em += t * t;
        t = cm.y - xq.y; em += t * t;
        t = cm.z - xq.z; em += t * t;
        t = cm.w - xq.w; em += t * t;
        t = cs.x - xq.x; es += t * t;
        t = cs.y - xq.y; es += t * t;
        t = cs.z - xq.z; es += t * t;
        t = cs.w - xq.w; es += t * t;
    }
#pragma unroll
    for (int off = 32; off; off >>= 1) {
        em += __shfl_down(em, off, 64);
        es += __shfl_down(es, off, 64);
    }
    __shared__ float sm[8];
    if (lane == 0) {
        sm[wv] = em; sm[4 + wv] = es;
        used[A] = 1;  // benign race: same value
    }
    __syncthreads();
    if (threadIdx.x == 0) {
        lossPart[blockIdx.x] = make_float2(sm[0] + sm[1] + sm[2] + sm[3],
                                           sm[4] + sm[5] + sm[6] + sm[7]);
    }
}

// ---------------------------------------------------------------------------
// Reduce 8192 loss partials + count used codes + write scalars + zero ms_k_i.
__global__ __launch_bounds__(256) void finalize_kernel(
    const int* __restrict__ used, const float2* __restrict__ lossPart,
    const int* __restrict__ training, float* __restrict__ out)
{
    int tid = threadIdx.x;
    int cnt = 0;
    for (int i = tid; i < 1024; i += 256) cnt += (used[i] != 0);
    float em = 0.f, es = 0.f;
    for (int i = tid; i < NBLK_RG; i += 256) {
        float2 p = lossPart[i];
        em += p.x; es += p.y;
    }
#pragma unroll
    for (int off = 32; off; off >>= 1) {
        cnt += __shfl_down(cnt, off, 64);
        em += __shfl_down(em, off, 64);
        es += __shfl_down(es, off, 64);
    }
    __shared__ int sc[4];
    __shared__ float se[4], ss[4];
    if ((tid & 63) == 0) { sc[tid >> 6] = cnt; se[tid >> 6] = em; ss[tid >> 6] = es; }
    __syncthreads();
    if (tid == 0) {
        int total = sc[0] + sc[1] + sc[2] + sc[3];
        float tl = 0.f;
        if (*training) {
            float l0 = se[0] + se[1] + se[2] + se[3];
            float l1 = ss[0] + ss[1] + ss[2] + ss[3];
            tl = 1.25f * (l0 + l1) * (1.0f / ((float)N_ROWS * (float)DK));
        }
        out[LOSS_OFF] = tl;
        out[UNIQ_OFF] = (float)total;
    }
    for (int i = tid; i < 8192; i += 256) out[MSK_OFF + i] = 0.f;
}

// ---------------------------------------------------------------------------
extern "C" void kernel_launch(void* const* d_in, const int* in_sizes, int n_in,
                              void* d_out, int out_size, void* d_ws, size_t ws_size,
                              hipStream_t stream) {
    const float* x = (const float*)d_in[0];
    const float* c = (const float*)d_in[1];
    const float* W1 = (const float*)d_in[2];
    const float* b1 = (const float*)d_in[3];
    const float* W2 = (const float*)d_in[4];
    const float* b2 = (const float*)d_in[5];
    const int* training = (const int*)d_in[6];
    float* out = (float*)d_out;

    // ws layout (all offsets 16B aligned); total ~43 MB
    char* p = (char*)d_ws;
    float* CB = (float*)p;          p += (size_t)NCB * DK * 4;       // 3,670,016
    _Float16* xh = (_Float16*)p;    p += (size_t)N_ROWS * DK * 2;    // 33,554,432
    _Float16* cbh = (_Float16*)p;   p += (size_t)NCB * DK * 2;       // 1,835,008
    uint2* candbuf = (uint2*)p;     p += (size_t)N_ROWS * NTILE * 8; // 3,670,016
    float* norms = (float*)p;       p += NCB * 4;                    // 7,168
    float2* lossPart = (float2*)p;  p += (size_t)NBLK_RG * 8;        // 65,536
    int* used = (int*)p;            p += 4096;

    build_subcb<<<dim3(8, 112), dim3(256), 0, stream>>>(c, W1, b1, W2, b2, CB, cbh);
    row_norms<<<dim3(NCB), dim3(64), 0, stream>>>(CB, norms);
    cvt_x<<<dim3(8192), dim3(256), 0, stream>>>(x, xh, used);
    gemm_topk<<<dim3(896), dim3(512), 0, stream>>>(xh, cbh, norms, candbuf);
    rescue_gather<<<dim3(NBLK_RG), dim3(256), 0, stream>>>(
        x, CB, norms, candbuf, out + MAIN_OFF, out + SUB_OFF, lossPart, used);
    finalize_kernel<<<dim3(1), dim3(256), 0, stream>>>(used, lossPart, training, out);
}

// Round 3
// 422.359 us; speedup vs baseline: 1.0262x; 1.0262x over previous
//
#include <hip/hip_runtime.h>
#include <cstdint>

typedef unsigned short ushort_t;
typedef unsigned int uint_t;
typedef _Float16 f16x8 __attribute__((ext_vector_type(8)));
typedef float f32x4 __attribute__((ext_vector_type(4)));

#define N_ROWS 32768
#define DK 512
#define NC_MAIN 1024
#define NCB 1792  // 1024 + 512 + 256
#define NTILE 14  // 1792 / 128 (candidate tile granularity, unchanged)
#define NBLK_RG 8192  // rescue_gather blocks (4 rows each)

// d_out layout (floats, concatenated reference outputs)
#define MAIN_OFF 0
#define SUB_OFF  16777216
#define LOSS_OFF 33554432
#define MSK_OFF  33554433
#define UNIQ_OFF 33562625

__device__ __forceinline__ uint_t umin_(uint_t a, uint_t b) { return a < b ? a : b; }
__device__ __forceinline__ uint_t umax_(uint_t a, uint_t b) { return a > b ? a : b; }

// ---------------------------------------------------------------------------
// Build combined codebook CB[1792][512] (fp32) AND its f16 copy cbh.
// rows 0..1023 copy of c; 1024..1535 = W1@c+b1; 1536..1791 = W2@c+b2.
__global__ __launch_bounds__(256) void build_subcb(
    const float* __restrict__ c, const float* __restrict__ W1,
    const float* __restrict__ b1, const float* __restrict__ W2,
    const float* __restrict__ b2, float* __restrict__ CB,
    _Float16* __restrict__ cbh)
{
    int tid = threadIdx.x;
    int tx = tid & 63, ty = tid >> 6;
    int col = blockIdx.x * 64 + tx;
    int row0 = blockIdx.y * 16 + ty * 4;
    if (row0 < 1024) {
#pragma unroll
        for (int r = 0; r < 4; ++r) {
            float v = c[(row0 + r) * DK + col];
            CB[(row0 + r) * DK + col] = v;
            cbh[(row0 + r) * DK + col] = (_Float16)v;
        }
    } else {
        int i0 = row0 - 1024;
        const float* W;
        const float* b;
        if (i0 < 512) { W = W1; b = b1; }
        else          { W = W2; b = b2; i0 -= 512; }
        float acc[4] = {0.f, 0.f, 0.f, 0.f};
#pragma unroll 8
        for (int j = 0; j < 1024; ++j) {
            float cv = c[j * DK + col];
#pragma unroll
            for (int r = 0; r < 4; ++r)
                acc[r] += W[(i0 + r) * 1024 + j] * cv;
        }
#pragma unroll
        for (int r = 0; r < 4; ++r) {
            float v = acc[r] + b[i0 + r];
            CB[(row0 + r) * DK + col] = v;
            cbh[(row0 + r) * DK + col] = (_Float16)v;
        }
    }
}

// ---------------------------------------------------------------------------
__global__ __launch_bounds__(64) void row_norms(const float* __restrict__ CB,
                                                float* __restrict__ norms) {
    int row = blockIdx.x;
    int lane = threadIdx.x;
    const float4* p = (const float4*)(CB + (size_t)row * DK);
    float s = 0.f;
#pragma unroll
    for (int i = lane; i < 128; i += 64) {
        float4 v = p[i];
        s += v.x * v.x + v.y * v.y + v.z * v.z + v.w * v.w;
    }
#pragma unroll
    for (int off = 32; off; off >>= 1) s += __shfl_down(s, off, 64);
    if (lane == 0) norms[row] = s;
}

// ---------------------------------------------------------------------------
// fp32 -> f16 (RN) for x, 8 elems/thread; also zeroes `used` (init fused).
__global__ __launch_bounds__(256) void cvt_x(const float* __restrict__ in,
                                             _Float16* __restrict__ out,
                                             int* __restrict__ used) {
    int i = blockIdx.x * 256 + threadIdx.x;
    if (i < 1024) used[i] = 0;
    const float4* p = (const float4*)in + (size_t)i * 2;
    float4 a = p[0], b = p[1];
    f16x8 o;
    o[0] = (_Float16)a.x; o[1] = (_Float16)a.y; o[2] = (_Float16)a.z; o[3] = (_Float16)a.w;
    o[4] = (_Float16)b.x; o[5] = (_Float16)b.y; o[6] = (_Float16)b.z; o[7] = (_Float16)b.w;
    *((f16x8*)out + i) = o;
}

// ---------------------------------------------------------------------------
__device__ __forceinline__ void async16(void* lds, const void* g) {
    __builtin_amdgcn_global_load_lds(
        (const __attribute__((address_space(1))) unsigned int*)(uintptr_t)g,
        (__attribute__((address_space(3))) unsigned int*)(uintptr_t)lds,
        16, 0, 0);
}

// ---------------------------------------------------------------------------
// MFMA f16 GEMM S = xh . cbh^T, 256x256 tile, BK=64, 8 waves (2Mx4N).
// Intra-tile software pipeline: ds_read clumps interleaved between MFMA
// clusters; compiler's counted lgkmcnt auto-waits let wave W's later reads
// drain on the LDS pipe while its earlier MFMAs occupy the matrix pipe.
// Barriers ONLY at tile boundaries (2/tile vs 8/tile lockstep-phase):
//   B1 after M4 (every wave's lgkm==0 there -> all reads of buffer b done)
//   stage tile t+2 into buffer b (WAR-safe after B1)
//   vmcnt(8) gate (t+1's 8 loads landed; t+2's 8 stay in flight = T4)
//   B2, then next tile reads buffer b^1.
// T2 swizzle unchanged: byte' ^= (((row>>1)&3)<<4) ^ (((row>>3)&1)<<6),
// pre-applied to global source (linear LDS dest) and to ds_read addrs.
__global__ __launch_bounds__(512, 2) void gemm_topk(
    const _Float16* __restrict__ xh, const _Float16* __restrict__ cbh,
    const float* __restrict__ norms, uint2* __restrict__ candbuf)
{
    __shared__ __align__(16) ushort_t As[2][2][256 * 32];  // 64 KiB
    __shared__ __align__(16) ushort_t Bs[2][2][256 * 32];  // 64 KiB

    const int tid = threadIdx.x;
    const int lane = tid & 63;
    const int wid = tid >> 6;
    const int wy = wid >> 2, wx = wid & 3;
    const int lane15 = lane & 15, q = lane >> 4;

    // XCD-aware remap: 896 blocks = 8 xcd * 112 slots; same-xcd consecutive
    // slots share an A row-strip (7 tileP each) -> strip stays in that XCD L2.
    const int bid = blockIdx.x;
    const int xcd = bid & 7;
    const int slot = bid >> 3;            // 0..111
    const int tileP = slot % 7;           // 256-col pair-tile 0..6
    const int rowG = slot / 7;            // 0..15
    const int rowBase = (rowG * 8 + xcd) * 256;
    const int c0 = tileP * 256;

    // staging: linear LDS dest, inverse-swizzled global source.
    size_t aoff[2], boff[2];
    int ldsd[2];
#pragma unroll
    for (int i = 0; i < 2; ++i) {
        int d16 = i * 512 + tid;          // 16B granule index in 16KiB region
        int row = d16 >> 2, g = d16 & 3;
        int srow = row ^ ((row >> 3) & 1);
        int sg = g ^ ((row >> 1) & 3);
        aoff[i] = (size_t)(rowBase + srow) * DK + (size_t)(sg * 8);
        boff[i] = (size_t)(c0 + srow) * DK + (size_t)(sg * 8);
        ldsd[i] = d16 * 8;                // f16 elements
    }

#define STG_A(BUF, KS, KT) do { \
        async16(&As[(BUF)][(KS)][ldsd[0]], xh + aoff[0] + (KT) * 64 + (KS) * 32); \
        async16(&As[(BUF)][(KS)][ldsd[1]], xh + aoff[1] + (KT) * 64 + (KS) * 32); \
    } while (0)
#define STG_B(BUF, KS, KT) do { \
        async16(&Bs[(BUF)][(KS)][ldsd[0]], cbh + boff[0] + (KT) * 64 + (KS) * 32); \
        async16(&Bs[(BUF)][(KS)][ldsd[1]], cbh + boff[1] + (KT) * 64 + (KS) * 32); \
    } while (0)

    // swizzled fragment read offsets (f16 units within one [256][32] region)
    int rdA[8], rdB[4];
#pragma unroll
    for (int mr = 0; mr < 8; ++mr) {
        int rl = wy * 128 + mr * 16 + lane15;
        rdA[mr] = (rl ^ ((rl >> 3) & 1)) * 32 + (q ^ ((rl >> 1) & 3)) * 8;
    }
#pragma unroll
    for (int nc = 0; nc < 4; ++nc) {
        int cl = wx * 64 + nc * 16 + lane15;
        rdB[nc] = (cl ^ ((cl >> 3) & 1)) * 32 + (q ^ ((cl >> 1) & 3)) * 8;
    }

    f32x4 acc[8][4];
#pragma unroll
    for (int mr = 0; mr < 8; ++mr)
#pragma unroll
        for (int nc = 0; nc < 4; ++nc) acc[mr][nc] = (f32x4)0.f;

    // ---- prologue: stage tile0 (8 loads) + tile1 (8 loads) ----
    STG_A(0, 0, 0); STG_B(0, 0, 0); STG_A(0, 1, 0); STG_B(0, 1, 0);
    STG_A(1, 0, 1); STG_B(1, 0, 1); STG_A(1, 1, 1); STG_B(1, 1, 1);
    asm volatile("s_waitcnt vmcnt(8)" ::: "memory");   // tile0 landed
    __builtin_amdgcn_s_barrier();

#pragma unroll
    for (int t = 0; t < 8; ++t) {
        const int b = t & 1;
        f16x8 b0[4], b1v[4], a0lo[4], a0hi[4], a1lo[4], a1hi[4];
        // R1: ks0 B frags + A lo (8 reads)
#pragma unroll
        for (int nc = 0; nc < 4; ++nc) b0[nc] = *(const f16x8*)&Bs[b][0][rdB[nc]];
#pragma unroll
        for (int mr = 0; mr < 4; ++mr) a0lo[mr] = *(const f16x8*)&As[b][0][rdA[mr]];
        // R2: ks0 A hi (4 reads)
#pragma unroll
        for (int mr = 0; mr < 4; ++mr) a0hi[mr] = *(const f16x8*)&As[b][0][rdA[4 + mr]];
        __builtin_amdgcn_sched_barrier(0);
        // M1: ks0, rows 0..63  (waits only R1 via counted lgkmcnt)
        __builtin_amdgcn_s_setprio(1);
#pragma unroll
        for (int mr = 0; mr < 4; ++mr)
#pragma unroll
            for (int nc = 0; nc < 4; ++nc)
                acc[mr][nc] = __builtin_amdgcn_mfma_f32_16x16x32_f16(
                    a0lo[mr], b0[nc], acc[mr][nc], 0, 0, 0);
        __builtin_amdgcn_s_setprio(0);
        __builtin_amdgcn_sched_barrier(0);
        // R3: ks1 B frags + A lo (8 reads) -- drain under M1/M2
#pragma unroll
        for (int nc = 0; nc < 4; ++nc) b1v[nc] = *(const f16x8*)&Bs[b][1][rdB[nc]];
#pragma unroll
        for (int mr = 0; mr < 4; ++mr) a1lo[mr] = *(const f16x8*)&As[b][1][rdA[mr]];
        __builtin_amdgcn_sched_barrier(0);
        // M2: ks0, rows 64..127 (waits R2)
        __builtin_amdgcn_s_setprio(1);
#pragma unroll
        for (int mr = 0; mr < 4; ++mr)
#pragma unroll
            for (int nc = 0; nc < 4; ++nc)
                acc[4 + mr][nc] = __builtin_amdgcn_mfma_f32_16x16x32_f16(
                    a0hi[mr], b0[nc], acc[4 + mr][nc], 0, 0, 0);
        __builtin_amdgcn_s_setprio(0);
        __builtin_amdgcn_sched_barrier(0);
        // R4: ks1 A hi (4 reads)
#pragma unroll
        for (int mr = 0; mr < 4; ++mr) a1hi[mr] = *(const f16x8*)&As[b][1][rdA[4 + mr]];
        __builtin_amdgcn_sched_barrier(0);
        // M3: ks1, rows 0..63 (waits R3)
        __builtin_amdgcn_s_setprio(1);
#pragma unroll
        for (int mr = 0; mr < 4; ++mr)
#pragma unroll
            for (int nc = 0; nc < 4; ++nc)
                acc[mr][nc] = __builtin_amdgcn_mfma_f32_16x16x32_f16(
                    a1lo[mr], b1v[nc], acc[mr][nc], 0, 0, 0);
        __builtin_amdgcn_s_setprio(0);
        __builtin_amdgcn_sched_barrier(0);
        // M4: ks1, rows 64..127 (waits R4 -> wave's lgkm fully drained)
        __builtin_amdgcn_s_setprio(1);
#pragma unroll
        for (int mr = 0; mr < 4; ++mr)
#pragma unroll
            for (int nc = 0; nc < 4; ++nc)
                acc[4 + mr][nc] = __builtin_amdgcn_mfma_f32_16x16x32_f16(
                    a1hi[mr], b1v[nc], acc[4 + mr][nc], 0, 0, 0);
        __builtin_amdgcn_s_setprio(0);
        __builtin_amdgcn_sched_barrier(0);
        // ---- tile boundary ----
        __builtin_amdgcn_s_barrier();      // all waves done reading buffer b
        if (t + 2 < 8) {                   // stage t+2 into buffer b (8 loads)
            STG_A(b, 0, t + 2); STG_B(b, 0, t + 2);
            STG_A(b, 1, t + 2); STG_B(b, 1, t + 2);
        }
        if (t < 7) {
            if (t + 2 < 8) asm volatile("s_waitcnt vmcnt(8)" ::: "memory");
            else           asm volatile("s_waitcnt vmcnt(0)" ::: "memory");
        }
        __builtin_amdgcn_sched_barrier(0);
        __builtin_amdgcn_s_barrier();      // t+1 data visible to all waves
    }
#undef STG_A
#undef STG_B

    // ---------------- epilogue: per-row top-2 per 128-col tile -------------
    // cand overlays As[0] (disjoint from As[1]/Bs; all reads of As[0] drained
    // by the t=6 boundary; both t=7 barriers passed before any cand write).
    uint2 (*cand)[4] = (uint2(*)[4])(void*)&As[0][0][0];  // [256 rows][4 wx]

    float nrm[4];
    uint_t colGlob[4];
#pragma unroll
    for (int nc = 0; nc < 4; ++nc) {
        colGlob[nc] = (uint_t)(c0 + wx * 64 + nc * 16 + lane15);
        nrm[nc] = norms[colGlob[nc]];
    }

#pragma unroll
    for (int mr = 0; mr < 8; ++mr) {
#pragma unroll
        for (int r = 0; r < 4; ++r) {
            uint_t k[4];
#pragma unroll
            for (int nc = 0; nc < 4; ++nc) {
                float s = fmaf(-2.f, acc[mr][nc][r], nrm[nc]);
                uint_t bb = __float_as_uint(s);
                uint_t u = bb ^ ((uint_t)((int)bb >> 31) | 0x80000000u);
                k[nc] = (u & 0xFFFFF800u) | colGlob[nc];
            }
            uint_t lo01 = umin_(k[0], k[1]), hi01 = umax_(k[0], k[1]);
            uint_t lo23 = umin_(k[2], k[3]), hi23 = umax_(k[2], k[3]);
            uint_t k1 = umin_(lo01, lo23);
            uint_t k2 = umin_(umin_(hi01, hi23), umax_(lo01, lo23));
#pragma unroll
            for (int m = 1; m <= 8; m <<= 1) {
                uint_t o1 = __shfl_xor(k1, m, 64);
                uint_t o2 = __shfl_xor(k2, m, 64);
                uint_t n1 = umin_(k1, o1);
                uint_t n2 = umin_(umax_(k1, o1), umin_(k2, o2));
                k1 = n1; k2 = n2;
            }
            if (lane15 == 0) {
                int rloc = wy * 128 + mr * 16 + q * 4 + r;
                cand[rloc][wx] = make_uint2(k1, k2);
            }
        }
    }
    __syncthreads();
    {
        int half = tid >> 8;        // 0..1 -> which 128-col tile of the pair
        int row = tid & 255;
        uint2 a = cand[row][half * 2], b2 = cand[row][half * 2 + 1];
        uint_t k1 = umin_(a.x, b2.x);
        uint_t k2 = umin_(umax_(a.x, b2.x), umin_(a.y, b2.y));
        candbuf[(size_t)(rowBase + row) * NTILE + (tileP * 2 + half)] =
            make_uint2(k1, k2);
    }
}

// ---------------------------------------------------------------------------
// Per x-row: merge tile candidate keys per segment (top-4, pure u32 min/max on
// wave-uniform values), rescore exactly in fp32, pick argmin (tie -> lowest
// idx; idx lives in key low bits so key order matches), gather rows, write
// outputs, per-block loss partials, mark used. One wave per row.
__device__ __forceinline__ void push4u(uint_t v, uint_t* bs) {
#pragma unroll
    for (int j = 0; j < 4; ++j) {
        uint_t lo = umin_(v, bs[j]);
        uint_t hi = umax_(v, bs[j]);
        bs[j] = lo; v = hi;
    }
}

__global__ __launch_bounds__(256) void rescue_gather(
    const float* __restrict__ x, const float* __restrict__ CB,
    const float* __restrict__ norms, const uint2* __restrict__ candbuf,
    float* __restrict__ main_out, float* __restrict__ sub_out,
    float2* __restrict__ lossPart, int* __restrict__ used)
{
    const int lane = threadIdx.x & 63;
    const int wv = threadIdx.x >> 6;
    const int r = blockIdx.x * 4 + wv;

    const float4* xp = (const float4*)(x + (size_t)r * DK) + lane * 2;
    float4 xa = xp[0], xb = xp[1];

    const uint2* cbp = candbuf + (size_t)r * NTILE;

    int si[12];
    {
        uint_t bs[4];
        // main: tiles 0..7
#pragma unroll
        for (int j = 0; j < 4; ++j) bs[j] = 0xFFFFFFFFu;
#pragma unroll
        for (int t = 0; t < 8; ++t) {
            uint2 e = cbp[t];
            push4u(__builtin_amdgcn_readfirstlane(e.x), bs);
            push4u(__builtin_amdgcn_readfirstlane(e.y), bs);
        }
#pragma unroll
        for (int j = 0; j < 4; ++j) si[j] = (int)(bs[j] & 2047u);
        // s1: tiles 8..11
#pragma unroll
        for (int j = 0; j < 4; ++j) bs[j] = 0xFFFFFFFFu;
#pragma unroll
        for (int t = 8; t < 12; ++t) {
            uint2 e = cbp[t];
            push4u(__builtin_amdgcn_readfirstlane(e.x), bs);
            push4u(__builtin_amdgcn_readfirstlane(e.y), bs);
        }
#pragma unroll
        for (int j = 0; j < 4; ++j) si[4 + j] = (int)(bs[j] & 2047u);
        // s2: tiles 12..13 (exactly 4 candidates)
#pragma unroll
        for (int j = 0; j < 4; ++j) bs[j] = 0xFFFFFFFFu;
#pragma unroll
        for (int t = 12; t < 14; ++t) {
            uint2 e = cbp[t];
            push4u(__builtin_amdgcn_readfirstlane(e.x), bs);
            push4u(__builtin_amdgcn_readfirstlane(e.y), bs);
        }
#pragma unroll
        for (int j = 0; j < 4; ++j) si[8 + j] = (int)(bs[j] & 2047u);
    }

    // exact fp32 dots for all 12 candidates
    float d[12];
#pragma unroll
    for (int k = 0; k < 12; ++k) {
        const float4* cp = (const float4*)(CB + (size_t)si[k] * DK) + lane * 2;
        float4 a = cp[0], b = cp[1];
        d[k] = xa.x * a.x + xa.y * a.y + xa.z * a.z + xa.w * a.w
             + xb.x * b.x + xb.y * b.y + xb.z * b.z + xb.w * b.w;
    }
#pragma unroll
    for (int off = 32; off; off >>= 1)
#pragma unroll
        for (int k = 0; k < 12; ++k) d[k] += __shfl_xor(d[k], off, 64);

    float sc[12];
#pragma unroll
    for (int k = 0; k < 12; ++k) sc[k] = norms[si[k]] - 2.f * d[k];

    int pick[3];
#pragma unroll
    for (int g = 0; g < 3; ++g) {
        float bv = sc[g * 4]; int bidx = si[g * 4];
#pragma unroll
        for (int k = 1; k < 4; ++k) {
            float v = sc[g * 4 + k]; int idx = si[g * 4 + k];
            if (v < bv || (v == bv && idx < bidx)) { bv = v; bidx = idx; }
        }
        pick[g] = bidx;
    }
    const int A = pick[0], B = pick[1], C = pick[2];

    // gather + write + loss
    const float4* pa = (const float4*)(CB + (size_t)A * DK) + lane * 2;
    const float4* pb = (const float4*)(CB + (size_t)B * DK) + lane * 2;
    const float4* pc = (const float4*)(CB + (size_t)C * DK) + lane * 2;
    float4* mo = (float4*)(main_out + (size_t)r * DK) + lane * 2;
    float4* so = (float4*)(sub_out + (size_t)r * DK) + lane * 2;
    float em = 0.f, es = 0.f;
#pragma unroll
    for (int i = 0; i < 2; ++i) {
        float4 xq = (i == 0) ? xa : xb;
        float4 cm = pa[i];
        float4 q1 = pb[i];
        float4 q2 = pc[i];
        float4 cs;
        cs.x = 0.5f * (q1.x + q2.x);
        cs.y = 0.5f * (q1.y + q2.y);
        cs.z = 0.5f * (q1.z + q2.z);
        cs.w = 0.5f * (q1.w + q2.w);
        mo[i] = cm;
        so[i] = cs;
        float t;
        t = cm.x - xq.x; em += t * t;
        t = cm.y - xq.y; em += t * t;
        t = cm.z - xq.z; em += t * t;
        t = cm.w - xq.w; em += t * t;
        t = cs.x - xq.x; es += t * t;
        t = cs.y - xq.y; es += t * t;
        t = cs.z - xq.z; es += t * t;
        t = cs.w - xq.w; es += t * t;
    }
#pragma unroll
    for (int off = 32; off; off >>= 1) {
        em += __shfl_down(em, off, 64);
        es += __shfl_down(es, off, 64);
    }
    __shared__ float sm[8];
    if (lane == 0) {
        sm[wv] = em; sm[4 + wv] = es;
        used[A] = 1;  // benign race: same value
    }
    __syncthreads();
    if (threadIdx.x == 0) {
        lossPart[blockIdx.x] = make_float2(sm[0] + sm[1] + sm[2] + sm[3],
                                           sm[4] + sm[5] + sm[6] + sm[7]);
    }
}

// ---------------------------------------------------------------------------
// Reduce 8192 loss partials + count used codes + write scalars + zero ms_k_i.
__global__ __launch_bounds__(256) void finalize_kernel(
    const int* __restrict__ used, const float2* __restrict__ lossPart,
    const int* __restrict__ training, float* __restrict__ out)
{
    int tid = threadIdx.x;
    int cnt = 0;
    for (int i = tid; i < 1024; i += 256) cnt += (used[i] != 0);
    float em = 0.f, es = 0.f;
    for (int i = tid; i < NBLK_RG; i += 256) {
        float2 p = lossPart[i];
        em += p.x; es += p.y;
    }
#pragma unroll
    for (int off = 32; off; off >>= 1) {
        cnt += __shfl_down(cnt, off, 64);
        em += __shfl_down(em, off, 64);
        es += __shfl_down(es, off, 64);
    }
    __shared__ int sc[4];
    __shared__ float se[4], ss[4];
    if ((tid & 63) == 0) { sc[tid >> 6] = cnt; se[tid >> 6] = em; ss[tid >> 6] = es; }
    __syncthreads();
    if (tid == 0) {
        int total = sc[0] + sc[1] + sc[2] + sc[3];
        float tl = 0.f;
        if (*training) {
            float l0 = se[0] + se[1] + se[2] + se[3];
            float l1 = ss[0] + ss[1] + ss[2] + ss[3];
            tl = 1.25f * (l0 + l1) * (1.0f / ((float)N_ROWS * (float)DK));
        }
        out[LOSS_OFF] = tl;
        out[UNIQ_OFF] = (float)total;
    }
    for (int i = tid; i < 8192; i += 256) out[MSK_OFF + i] = 0.f;
}

// ---------------------------------------------------------------------------
extern "C" void kernel_launch(void* const* d_in, const int* in_sizes, int n_in,
                              void* d_out, int out_size, void* d_ws, size_t ws_size,
                              hipStream_t stream) {
    const float* x = (const float*)d_in[0];
    const float* c = (const float*)d_in[1];
    const float* W1 = (const float*)d_in[2];
    const float* b1 = (const float*)d_in[3];
    const float* W2 = (const float*)d_in[4];
    const float* b2 = (const float*)d_in[5];
    const int* training = (const int*)d_in[6];
    float* out = (float*)d_out;

    // ws layout (all offsets 16B aligned); total ~43 MB
    char* p = (char*)d_ws;
    float* CB = (float*)p;          p += (size_t)NCB * DK * 4;       // 3,670,016
    _Float16* xh = (_Float16*)p;    p += (size_t)N_ROWS * DK * 2;    // 33,554,432
    _Float16* cbh = (_Float16*)p;   p += (size_t)NCB * DK * 2;       // 1,835,008
    uint2* candbuf = (uint2*)p;     p += (size_t)N_ROWS * NTILE * 8; // 3,670,016
    float* norms = (float*)p;       p += NCB * 4;                    // 7,168
    float2* lossPart = (float2*)p;  p += (size_t)NBLK_RG * 8;        // 65,536
    int* used = (int*)p;            p += 4096;

    build_subcb<<<dim3(8, 112), dim3(256), 0, stream>>>(c, W1, b1, W2, b2, CB, cbh);
    row_norms<<<dim3(NCB), dim3(64), 0, stream>>>(CB, norms);
    cvt_x<<<dim3(8192), dim3(256), 0, stream>>>(x, xh, used);
    gemm_topk<<<dim3(896), dim3(512), 0, stream>>>(xh, cbh, norms, candbuf);
    rescue_gather<<<dim3(NBLK_RG), dim3(256), 0, stream>>>(
        x, CB, norms, candbuf, out + MAIN_OFF, out + SUB_OFF, lossPart, used);
    finalize_kernel<<<dim3(1), dim3(256), 0, stream>>>(used, lossPart, training, out);
}